// Round 4
// baseline (531.653 us; speedup 1.0000x reference)
//
#include <hip/hip_runtime.h>
#include <math.h>

// Problem constants (match reference setup_inputs()).
#define NNODES 10000
#define MPAD   10112           // 79 * 128 (MFMA M-tile padding)
#define NEDGES 80000           // directed edges before self loops
#define ETOT   (NEDGES + NNODES)

typedef __attribute__((ext_vector_type(4))) float f32x4;
typedef __attribute__((ext_vector_type(8))) short bf16x8;
typedef __attribute__((ext_vector_type(4))) unsigned short u16x4;

__device__ inline unsigned short f2bf(float f) {
    unsigned int u = __float_as_uint(f);
    unsigned int r = (u + 0x7fffu + ((u >> 16) & 1u)) >> 16;
    return (unsigned short)r;
}
__device__ inline float bf2f(unsigned short h) {
    return __uint_as_float(((unsigned int)h) << 16);
}
__device__ inline float lrelu01(float v) { return (v > 0.f) ? v : 0.1f * v; }

// ---------------------------------------------------------------------------
// CSR build (group edges by destination). Rebuilt every launch (ws poisoned).
// ---------------------------------------------------------------------------
__global__ void count_deg(const int* __restrict__ ei, int* __restrict__ indeg,
                          int E, int n) {
    int i = blockIdx.x * blockDim.x + threadIdx.x;
    if (i >= E + n) return;
    int dst = (i < E) ? ei[E + i] : (i - E);
    atomicAdd(&indeg[dst], 1);
}

__global__ void scan_rowptr(const int* __restrict__ indeg, int* __restrict__ row_ptr,
                            int* __restrict__ cursor, int n) {
    __shared__ int sums[1024];
    int tid = threadIdx.x;
    int per = (n + 1023) / 1024;
    int start = tid * per;
    int end = start + per; if (end > n) end = n;
    int s = 0;
    for (int i = start; i < end; ++i) s += indeg[i];
    sums[tid] = s;
    __syncthreads();
    for (int off = 1; off < 1024; off <<= 1) {
        int v = (tid >= off) ? sums[tid - off] : 0;
        __syncthreads();
        sums[tid] += v;
        __syncthreads();
    }
    int excl = (tid == 0) ? 0 : sums[tid - 1];
    for (int i = start; i < end; ++i) {
        row_ptr[i] = excl;
        cursor[i]  = excl;
        excl += indeg[i];
    }
    if (tid == 1023) row_ptr[n] = sums[1023];
}

__global__ void scatter_edges(const int* __restrict__ ei, int* __restrict__ cursor,
                              int* __restrict__ col, int E, int n) {
    int i = blockIdx.x * blockDim.x + threadIdx.x;
    if (i >= E + n) return;
    int src, dst;
    if (i < E) { src = ei[i]; dst = ei[E + i]; }
    else       { src = i - E; dst = i - E; }
    int pos = atomicAdd(&cursor[dst], 1);
    col[pos] = src;
}

// ---------------------------------------------------------------------------
// fp32 -> bf16 elementwise convert (for x).
// ---------------------------------------------------------------------------
__global__ void convert_bf16(const float* __restrict__ in, unsigned short* __restrict__ out,
                             int n) {
    int i = blockIdx.x * blockDim.x + threadIdx.x;
    if (i < n) out[i] = f2bf(in[i]);
}

// Transpose-convert W[K][N] fp32 -> Wt[N][K] bf16. K,N multiples of 32.
__global__ void transpose_bf16(const float* __restrict__ W, unsigned short* __restrict__ Wt,
                               int K, int N) {
    __shared__ float t[32][33];
    int kb = blockIdx.y * 32, nb = blockIdx.x * 32;
    int tx = threadIdx.x, ty = threadIdx.y;   // 32 x 8
    #pragma unroll
    for (int i = 0; i < 32; i += 8)
        t[ty + i][tx] = W[(size_t)(kb + ty + i) * N + nb + tx];
    __syncthreads();
    #pragma unroll
    for (int i = 0; i < 32; i += 8)
        Wt[(size_t)(nb + ty + i) * K + kb + tx] = f2bf(t[tx][ty + i]);
}

// ---------------------------------------------------------------------------
// bf16 MFMA GEMM: C[MPAD][N] (bf16 out) = A[MPAD][K] (bf16) @ Bt[N][K]^T.
// Tile 128x64, 256 threads = 4 waves, each wave 64x32 via 4x2 16x16x32 MFMAs.
// ---------------------------------------------------------------------------
#define GBM 128
#define GBN 64
#define GBK 32
__global__ __launch_bounds__(256) void gemm_mfma(const unsigned short* __restrict__ A,
                                                 const unsigned short* __restrict__ Bt,
                                                 unsigned short* __restrict__ C,
                                                 int N, int K) {
    __shared__ short As[GBM * GBK];
    __shared__ short Bs[GBN * GBK];
    int tid  = threadIdx.x;
    int wave = tid >> 6, lane = tid & 63;
    int bm = blockIdx.y * GBM;
    int bn = blockIdx.x * GBN;
    int wr = wave >> 1, wc = wave & 1;
    int lrow  = lane >> 2;
    int lkoff = (lane & 3) * 8;
    int row16 = lane & 15;
    int q8    = (lane >> 4) * 8;

    f32x4 acc[4][2];
    #pragma unroll
    for (int mi = 0; mi < 4; ++mi)
        #pragma unroll
        for (int ni = 0; ni < 2; ++ni) acc[mi][ni] = (f32x4){0.f, 0.f, 0.f, 0.f};

    for (int k0 = 0; k0 < K; k0 += GBK) {
        #pragma unroll
        for (int i = 0; i < 2; ++i) {
            int c = i * 4 + wave;
            int row = c * 16 + lrow;
            const unsigned short* gp = A + (size_t)(bm + row) * K + k0 + lkoff;
            __builtin_amdgcn_global_load_lds(
                (const __attribute__((address_space(1))) void*)gp,
                (__attribute__((address_space(3))) void*)&As[c * 512], 16, 0, 0);
        }
        {
            int row = wave * 16 + lrow;
            const unsigned short* gp = Bt + (size_t)(bn + row) * K + k0 + lkoff;
            __builtin_amdgcn_global_load_lds(
                (const __attribute__((address_space(1))) void*)gp,
                (__attribute__((address_space(3))) void*)&Bs[wave * 512], 16, 0, 0);
        }
        __syncthreads();
        bf16x8 af[4], bfr[2];
        #pragma unroll
        for (int mi = 0; mi < 4; ++mi)
            af[mi] = *(const bf16x8*)&As[(wr * 64 + mi * 16 + row16) * GBK + q8];
        #pragma unroll
        for (int ni = 0; ni < 2; ++ni)
            bfr[ni] = *(const bf16x8*)&Bs[(wc * 32 + ni * 16 + row16) * GBK + q8];
        #pragma unroll
        for (int mi = 0; mi < 4; ++mi)
            #pragma unroll
            for (int ni = 0; ni < 2; ++ni)
                acc[mi][ni] = __builtin_amdgcn_mfma_f32_16x16x32_bf16(
                    af[mi], bfr[ni], acc[mi][ni], 0, 0, 0);
        __syncthreads();
    }

    int rbase = bm + wr * 64 + (lane >> 4) * 4;
    int cbase = bn + wc * 32 + (lane & 15);
    #pragma unroll
    for (int mi = 0; mi < 4; ++mi)
        #pragma unroll
        for (int ni = 0; ni < 2; ++ni)
            #pragma unroll
            for (int r = 0; r < 4; ++r)
                C[(size_t)(rbase + mi * 16 + r) * N + cbase + ni * 16] =
                    f2bf(acc[mi][ni][r]);
}

// ---------------------------------------------------------------------------
// Tiny layer-4 GEMM: C[M][16] (bf16) = A[M][128] (bf16) @ W[128][16] (fp32).
// ---------------------------------------------------------------------------
__global__ __launch_bounds__(256) void gemm4(const unsigned short* __restrict__ A,
                                             const float* __restrict__ W,
                                             unsigned short* __restrict__ C, int M) {
    __shared__ float Ws[128 * 16];
    int tid = threadIdx.x;
    for (int i = tid; i < 2048; i += 256) Ws[i] = W[i];
    __syncthreads();
    int node = blockIdx.x * 16 + (tid >> 4);
    int n = tid & 15;
    if (node >= M) return;
    const unsigned short* ap = A + (size_t)node * 128;
    float acc = 0.f;
    #pragma unroll 8
    for (int k = 0; k < 128; ++k)
        acc += bf2f(ap[k]) * Ws[k * 16 + n];
    C[(size_t)node * 16 + n] = f2bf(acc);
}

// ---------------------------------------------------------------------------
// e_src[n,H], e_dst[n,H]: per-(node,head) dot of bf16 h[n,h,:] with a_src/a_dst.
// ---------------------------------------------------------------------------
__global__ __launch_bounds__(64) void attn_halves(const unsigned short* __restrict__ h,
                                                  const float* __restrict__ a_src,
                                                  const float* __restrict__ a_dst,
                                                  float* __restrict__ e_src,
                                                  float* __restrict__ e_dst,
                                                  int H, int C) {
    int wid = blockIdx.x;          // node*H + head
    int head = wid % H;
    int lane = threadIdx.x;
    const unsigned short* hp = h + (size_t)wid * C;
    float s1 = 0.f, s2 = 0.f;
    for (int c0 = lane * 4; c0 < C; c0 += 256) {
        u16x4 hv = *(const u16x4*)&hp[c0];
        f32x4 as = *(const f32x4*)&a_src[head * C + c0];
        f32x4 ad = *(const f32x4*)&a_dst[head * C + c0];
        #pragma unroll
        for (int j = 0; j < 4; ++j) {
            float v = bf2f(hv[j]);
            s1 += v * as[j];
            s2 += v * ad[j];
        }
    }
    #pragma unroll
    for (int off = 32; off; off >>= 1) {
        s1 += __shfl_down(s1, off);
        s2 += __shfl_down(s2, off);
    }
    if (lane == 0) { e_src[wid] = s1; e_dst[wid] = s2; }
}

// ---------------------------------------------------------------------------
// Normalized attention weights: alpha[i*H+head] = exp(el-m)/(sum exp + 1e-16),
// el = LeakyReLU_0.2(e_src[col[i]] + e_dst[dst]). One wave per (dst,head).
// ---------------------------------------------------------------------------
__global__ __launch_bounds__(64) void calc_alpha(const float* __restrict__ e_src,
                                                 const float* __restrict__ e_dst,
                                                 const int* __restrict__ row_ptr,
                                                 const int* __restrict__ col,
                                                 float* __restrict__ alpha,
                                                 int H) {
    int wid = blockIdx.x;              // node*H + head
    int node = wid / H;
    int head = wid - node * H;
    int lane = threadIdx.x;
    int rs = row_ptr[node], re = row_ptr[node + 1];
    float edv = e_dst[wid];

    float mx = -INFINITY;
    for (int i = rs + lane; i < re; i += 64) {
        float v = e_src[col[i] * H + head] + edv;
        v = (v > 0.f) ? v : 0.2f * v;
        mx = fmaxf(mx, v);
    }
    #pragma unroll
    for (int off = 32; off; off >>= 1) mx = fmaxf(mx, __shfl_down(mx, off));
    mx = __shfl(mx, 0);

    float dn = 0.f;
    for (int i = rs + lane; i < re; i += 64) {
        float v = e_src[col[i] * H + head] + edv;
        v = (v > 0.f) ? v : 0.2f * v;
        dn += __expf(v - mx);
    }
    #pragma unroll
    for (int off = 32; off; off >>= 1) dn += __shfl_down(dn, off);
    dn = __shfl(dn, 0);
    float rdn = 1.f / (dn + 1e-16f);

    for (int i = rs + lane; i < re; i += 64) {
        float v = e_src[col[i] * H + head] + edv;
        v = (v > 0.f) ? v : 0.2f * v;
        alpha[(size_t)i * H + head] = __expf(v - mx) * rdn;
    }
}

// ---------------------------------------------------------------------------
// Aggregation, wide (C=256, layer 1): wave = (node,head,chunk), 128 ch/wave
// via packed bf16x2 gathers. Pure gather-FMA: alpha precomputed. col/alpha
// preloaded into lane registers and shuffle-broadcast.
// ---------------------------------------------------------------------------
__global__ __launch_bounds__(64) void aggregate_wide(const unsigned int* __restrict__ h2,
                                                     const float* __restrict__ alpha,
                                                     const int* __restrict__ row_ptr,
                                                     const int* __restrict__ col,
                                                     const float* __restrict__ bias,
                                                     unsigned int* __restrict__ out2,
                                                     int H) {
    const int CW = 128;                // dwords per (node,head) row
    int wid = blockIdx.x;
    int chunk = wid & 1;
    int nh = wid >> 1;                 // node*H + head
    int node = nh / H;
    int head = nh - node * H;
    int lane = threadIdx.x;
    int rs = row_ptr[node], re = row_ptr[node + 1];

    float acc0 = 0.f, acc1 = 0.f;
    for (int base = rs; base < re; base += 64) {
        int cnt = re - base; if (cnt > 64) cnt = 64;
        int   myc = (lane < cnt) ? col[base + lane] : 0;
        float mya = (lane < cnt) ? alpha[(size_t)(base + lane) * H + head] : 0.f;
        #pragma unroll 2
        for (int j = 0; j < cnt; ++j) {
            int s   = __shfl(myc, j);
            float a = __shfl(mya, j);
            unsigned int hv = h2[(size_t)(s * H + head) * CW + chunk * 64 + lane];
            acc0 += a * bf2f((unsigned short)(hv & 0xffffu));
            acc1 += a * bf2f((unsigned short)(hv >> 16));
        }
    }

    int c0 = chunk * 128 + lane * 2;
    float v0 = lrelu01(acc0 + bias[head * 256 + c0]);
    float v1 = lrelu01(acc1 + bias[head * 256 + c0 + 1]);
    out2[(size_t)nh * CW + chunk * 64 + lane] =
        (unsigned int)f2bf(v0) | ((unsigned int)f2bf(v1) << 16);
}

// ---------------------------------------------------------------------------
// Aggregation, packed small C: HPW heads per wave, L=64/HPW lanes per head,
// C/2 packed dwords per head row. All sub-groups share the node's edge list.
// ---------------------------------------------------------------------------
template <int C, int HPW>
__global__ __launch_bounds__(64) void aggregate_packed(const unsigned int* __restrict__ h2,
                                                       const float* __restrict__ alpha,
                                                       const int* __restrict__ row_ptr,
                                                       const int* __restrict__ col,
                                                       const float* __restrict__ bias,
                                                       unsigned int* __restrict__ out2,
                                                       int H) {
    constexpr int L  = 64 / HPW;
    constexpr int CW = C / 2;
    int wid = blockIdx.x;              // node * (H/HPW) + headgroup
    int ng = H / HPW;
    int node = wid / ng;
    int hg   = wid - node * ng;
    int lane = threadIdx.x;
    int sub  = lane / L;
    int cpos = lane - sub * L;
    int head = hg * HPW + sub;
    int cposc = (cpos < CW) ? cpos : (CW - 1);   // clamp inactive lanes in-row
    int rs = row_ptr[node], re = row_ptr[node + 1];

    float acc0 = 0.f, acc1 = 0.f;
    for (int base = rs; base < re; base += L) {
        int cnt = re - base; if (cnt > L) cnt = L;
        int   myc = (cpos < cnt) ? col[base + cpos] : 0;
        float mya = (cpos < cnt) ? alpha[(size_t)(base + cpos) * H + head] : 0.f;
        #pragma unroll 2
        for (int j = 0; j < cnt; ++j) {
            int s   = __shfl(myc, j, L);
            float a = __shfl(mya, j, L);
            unsigned int hv = h2[(size_t)(s * H + head) * CW + cposc];
            acc0 += a * bf2f((unsigned short)(hv & 0xffffu));
            acc1 += a * bf2f((unsigned short)(hv >> 16));
        }
    }

    if (cpos < CW) {
        float v0 = lrelu01(acc0 + bias[head * C + 2 * cpos]);
        float v1 = lrelu01(acc1 + bias[head * C + 2 * cpos + 1]);
        out2[(size_t)(node * H + head) * CW + cpos] =
            (unsigned int)f2bf(v0) | ((unsigned int)f2bf(v1) << 16);
    }
}

// ---------------------------------------------------------------------------
// Layer 4 fused: aggregate (H=1, C=16) + bias + LeakyReLU(0.1) + row softmax.
// One wave per node; 8-lane groups hold 16 channels (2 per lane, packed).
// ---------------------------------------------------------------------------
__global__ __launch_bounds__(64) void agg4_softmax(const unsigned int* __restrict__ h2,
                                                   const float* __restrict__ alpha,
                                                   const int* __restrict__ row_ptr,
                                                   const int* __restrict__ col,
                                                   const float* __restrict__ bias,
                                                   float* __restrict__ out) {
    int node = blockIdx.x;
    int lane = threadIdx.x;
    int cpos = lane & 7;
    int rs = row_ptr[node], re = row_ptr[node + 1];

    float acc0 = 0.f, acc1 = 0.f;
    for (int base = rs; base < re; base += 8) {
        int cnt = re - base; if (cnt > 8) cnt = 8;
        int   myc = (cpos < cnt) ? col[base + cpos] : 0;
        float mya = (cpos < cnt) ? alpha[base + cpos] : 0.f;
        #pragma unroll 2
        for (int j = 0; j < cnt; ++j) {
            int s   = __shfl(myc, j, 8);
            float a = __shfl(mya, j, 8);
            unsigned int hv = h2[(size_t)s * 8 + cpos];
            acc0 += a * bf2f((unsigned short)(hv & 0xffffu));
            acc1 += a * bf2f((unsigned short)(hv >> 16));
        }
    }
    float v0 = lrelu01(acc0 + bias[2 * cpos]);
    float v1 = lrelu01(acc1 + bias[2 * cpos + 1]);

    // softmax over the 16 values held by each aligned 8-lane group
    float m = fmaxf(v0, v1);
    #pragma unroll
    for (int off = 4; off; off >>= 1) m = fmaxf(m, __shfl_xor(m, off));
    float e0 = __expf(v0 - m), e1 = __expf(v1 - m);
    float s = e0 + e1;
    #pragma unroll
    for (int off = 4; off; off >>= 1) s += __shfl_xor(s, off);
    float r = 1.f / s;
    if (lane < 8) {
        out[node * 16 + 2 * cpos]     = e0 * r;
        out[node * 16 + 2 * cpos + 1] = e1 * r;
    }
}

// ---------------------------------------------------------------------------
extern "C" void kernel_launch(void* const* d_in, const int* in_sizes, int n_in,
                              void* d_out, int out_size, void* d_ws, size_t ws_size,
                              hipStream_t stream) {
    const float* x   = (const float*)d_in[0];
    const int*   ei  = (const int*)d_in[1];
    const float* W1  = (const float*)d_in[2];
    const float* as1 = (const float*)d_in[3];
    const float* ad1 = (const float*)d_in[4];
    const float* b1  = (const float*)d_in[5];
    const float* W2  = (const float*)d_in[6];
    const float* as2 = (const float*)d_in[7];
    const float* ad2 = (const float*)d_in[8];
    const float* b2  = (const float*)d_in[9];
    const float* W3  = (const float*)d_in[10];
    const float* as3 = (const float*)d_in[11];
    const float* ad3 = (const float*)d_in[12];
    const float* b3  = (const float*)d_in[13];
    const float* W4  = (const float*)d_in[14];
    const float* as4 = (const float*)d_in[15];
    const float* ad4 = (const float*)d_in[16];
    const float* b4  = (const float*)d_in[17];

    char* ws = (char*)d_ws;
    size_t off = 0;
    auto alloc = [&](size_t bytes) -> void* {
        void* p = ws + off;
        off = (off + bytes + 255) & ~(size_t)255;
        return p;
    };
    unsigned short* hbuf = (unsigned short*)alloc((size_t)MPAD * 2560 * sizeof(short)); // GEMM out / attn input
    unsigned short* abuf = (unsigned short*)alloc((size_t)MPAD * 2560 * sizeof(short)); // bf16 GEMM A input
    unsigned short* W1t  = (unsigned short*)alloc((size_t)2560 * 128 * sizeof(short));
    unsigned short* W2t  = (unsigned short*)alloc((size_t)448 * 2560 * sizeof(short));
    unsigned short* W3t  = (unsigned short*)alloc((size_t)128 * 448 * sizeof(short));
    float* e_src  = (float*)alloc((size_t)NNODES * 10 * sizeof(float));
    float* e_dst  = (float*)alloc((size_t)NNODES * 10 * sizeof(float));
    float* alphab = (float*)alloc((size_t)ETOT * 10 * sizeof(float));
    int* indeg    = (int*)alloc(NNODES * sizeof(int));
    int* row_ptr  = (int*)alloc((NNODES + 1) * sizeof(int));
    int* cursor   = (int*)alloc(NNODES * sizeof(int));
    int* col      = (int*)alloc(ETOT * sizeof(int));
    (void)ws_size;

    // ---- CSR build ----
    hipMemsetAsync(indeg, 0, NNODES * sizeof(int), stream);
    int eb = (ETOT + 255) / 256;
    count_deg<<<eb, 256, 0, stream>>>(ei, indeg, NEDGES, NNODES);
    scan_rowptr<<<1, 1024, 0, stream>>>(indeg, row_ptr, cursor, NNODES);
    scatter_edges<<<eb, 256, 0, stream>>>(ei, cursor, col, NEDGES, NNODES);

    // ---- weight transposes + x convert ----
    transpose_bf16<<<dim3(2560 / 32, 128 / 32), dim3(32, 8), 0, stream>>>(W1, W1t, 128, 2560);
    transpose_bf16<<<dim3(448 / 32, 2560 / 32), dim3(32, 8), 0, stream>>>(W2, W2t, 2560, 448);
    transpose_bf16<<<dim3(128 / 32, 448 / 32), dim3(32, 8), 0, stream>>>(W3, W3t, 448, 128);
    convert_bf16<<<(NNODES * 128 + 255) / 256, 256, 0, stream>>>(x, abuf, NNODES * 128);

    const int Mb = MPAD / GBM;   // 79

    // ---- Layer 1: 128 -> 10 heads x 256, concat ----
    gemm_mfma<<<dim3(2560 / GBN, Mb), 256, 0, stream>>>(abuf, W1t, hbuf, 2560, 128);
    attn_halves<<<NNODES * 10, 64, 0, stream>>>(hbuf, as1, ad1, e_src, e_dst, 10, 256);
    calc_alpha<<<NNODES * 10, 64, 0, stream>>>(e_src, e_dst, row_ptr, col, alphab, 10);
    aggregate_wide<<<NNODES * 10 * 2, 64, 0, stream>>>(
        (const unsigned int*)hbuf, alphab, row_ptr, col, b1, (unsigned int*)abuf, 10);

    // ---- Layer 2: 2560 -> 8 heads x 56, concat ----
    gemm_mfma<<<dim3(448 / GBN, Mb), 256, 0, stream>>>(abuf, W2t, hbuf, 448, 2560);
    attn_halves<<<NNODES * 8, 64, 0, stream>>>(hbuf, as2, ad2, e_src, e_dst, 8, 56);
    calc_alpha<<<NNODES * 8, 64, 0, stream>>>(e_src, e_dst, row_ptr, col, alphab, 8);
    aggregate_packed<56, 2><<<NNODES * 4, 64, 0, stream>>>(
        (const unsigned int*)hbuf, alphab, row_ptr, col, b2, (unsigned int*)abuf, 8);

    // ---- Layer 3: 448 -> 4 heads x 32, concat ----
    gemm_mfma<<<dim3(128 / GBN, Mb), 256, 0, stream>>>(abuf, W3t, hbuf, 128, 448);
    attn_halves<<<NNODES * 4, 64, 0, stream>>>(hbuf, as3, ad3, e_src, e_dst, 4, 32);
    calc_alpha<<<NNODES * 4, 64, 0, stream>>>(e_src, e_dst, row_ptr, col, alphab, 4);
    aggregate_packed<32, 4><<<NNODES, 64, 0, stream>>>(
        (const unsigned int*)hbuf, alphab, row_ptr, col, b3, (unsigned int*)abuf, 4);

    // ---- Layer 4: 128 -> 1 head x 16, mean(=identity), + softmax fused ----
    gemm4<<<(NNODES + 15) / 16, 256, 0, stream>>>(abuf, W4, hbuf, NNODES);
    attn_halves<<<NNODES, 64, 0, stream>>>(hbuf, as4, ad4, e_src, e_dst, 1, 16);
    calc_alpha<<<NNODES, 64, 0, stream>>>(e_src, e_dst, row_ptr, col, alphab, 1);
    agg4_softmax<<<NNODES, 64, 0, stream>>>(
        (const unsigned int*)hbuf, alphab, row_ptr, col, b4, (float*)d_out);
}

// Round 5
// 404.548 us; speedup vs baseline: 1.3142x; 1.3142x over previous
//
#include <hip/hip_runtime.h>
#include <math.h>

// Problem constants (match reference setup_inputs()).
#define NNODES 10000
#define MPAD   10112           // 79 * 128 (MFMA M-tile padding)
#define NEDGES 80000           // directed edges before self loops
#define ETOT   (NEDGES + NNODES)

typedef __attribute__((ext_vector_type(4))) float f32x4;
typedef __attribute__((ext_vector_type(8))) short bf16x8;
typedef __attribute__((ext_vector_type(4))) unsigned short u16x4;
typedef __attribute__((ext_vector_type(4))) unsigned int u32x4;

__device__ inline unsigned short f2bf(float f) {
    unsigned int u = __float_as_uint(f);
    unsigned int r = (u + 0x7fffu + ((u >> 16) & 1u)) >> 16;
    return (unsigned short)r;
}
__device__ inline float bf2f(unsigned short h) {
    return __uint_as_float(((unsigned int)h) << 16);
}
__device__ inline float lrelu01(float v) { return (v > 0.f) ? v : 0.1f * v; }
__device__ inline float lrelu02(float v) { return (v > 0.f) ? v : 0.2f * v; }

// ---------------------------------------------------------------------------
// CSR build (group edges by destination). Rebuilt every launch (ws poisoned).
// ---------------------------------------------------------------------------
__global__ void count_deg(const int* __restrict__ ei, int* __restrict__ indeg,
                          int E, int n) {
    int i = blockIdx.x * blockDim.x + threadIdx.x;
    if (i >= E + n) return;
    int dst = (i < E) ? ei[E + i] : (i - E);
    atomicAdd(&indeg[dst], 1);
}

__global__ void scan_rowptr(const int* __restrict__ indeg, int* __restrict__ row_ptr,
                            int* __restrict__ cursor, int n) {
    __shared__ int sums[1024];
    int tid = threadIdx.x;
    int per = (n + 1023) / 1024;
    int start = tid * per;
    int end = start + per; if (end > n) end = n;
    int s = 0;
    for (int i = start; i < end; ++i) s += indeg[i];
    sums[tid] = s;
    __syncthreads();
    for (int off = 1; off < 1024; off <<= 1) {
        int v = (tid >= off) ? sums[tid - off] : 0;
        __syncthreads();
        sums[tid] += v;
        __syncthreads();
    }
    int excl = (tid == 0) ? 0 : sums[tid - 1];
    for (int i = start; i < end; ++i) {
        row_ptr[i] = excl;
        cursor[i]  = excl;
        excl += indeg[i];
    }
    if (tid == 1023) row_ptr[n] = sums[1023];
}

__global__ void scatter_edges(const int* __restrict__ ei, int* __restrict__ cursor,
                              int* __restrict__ col, int E, int n) {
    int i = blockIdx.x * blockDim.x + threadIdx.x;
    if (i >= E + n) return;
    int src, dst;
    if (i < E) { src = ei[i]; dst = ei[E + i]; }
    else       { src = i - E; dst = i - E; }
    int pos = atomicAdd(&cursor[dst], 1);
    col[pos] = src;
}

// ---------------------------------------------------------------------------
// fp32 -> bf16 elementwise convert (for x).
// ---------------------------------------------------------------------------
__global__ void convert_bf16(const float* __restrict__ in, unsigned short* __restrict__ out,
                             int n) {
    int i = blockIdx.x * blockDim.x + threadIdx.x;
    if (i < n) out[i] = f2bf(in[i]);
}

// Transpose-convert W[K][N] fp32 -> Wt[N][K] bf16. K,N multiples of 32.
__global__ void transpose_bf16(const float* __restrict__ W, unsigned short* __restrict__ Wt,
                               int K, int N) {
    __shared__ float t[32][33];
    int kb = blockIdx.y * 32, nb = blockIdx.x * 32;
    int tx = threadIdx.x, ty = threadIdx.y;   // 32 x 8
    #pragma unroll
    for (int i = 0; i < 32; i += 8)
        t[ty + i][tx] = W[(size_t)(kb + ty + i) * N + nb + tx];
    __syncthreads();
    #pragma unroll
    for (int i = 0; i < 32; i += 8)
        Wt[(size_t)(nb + ty + i) * K + kb + tx] = f2bf(t[tx][ty + i]);
}

// ---------------------------------------------------------------------------
// bf16 MFMA GEMM: C[MPAD][N] (bf16 out) = A[MPAD][K] (bf16) @ Bt[N][K]^T.
// Tile 128x64, 256 threads = 4 waves, each wave 64x32 via 4x2 16x16x32 MFMAs.
// ---------------------------------------------------------------------------
#define GBM 128
#define GBN 64
#define GBK 32
__global__ __launch_bounds__(256) void gemm_mfma(const unsigned short* __restrict__ A,
                                                 const unsigned short* __restrict__ Bt,
                                                 unsigned short* __restrict__ C,
                                                 int N, int K) {
    __shared__ short As[GBM * GBK];
    __shared__ short Bs[GBN * GBK];
    int tid  = threadIdx.x;
    int wave = tid >> 6, lane = tid & 63;
    int bm = blockIdx.y * GBM;
    int bn = blockIdx.x * GBN;
    int wr = wave >> 1, wc = wave & 1;
    int lrow  = lane >> 2;
    int lkoff = (lane & 3) * 8;
    int row16 = lane & 15;
    int q8    = (lane >> 4) * 8;

    f32x4 acc[4][2];
    #pragma unroll
    for (int mi = 0; mi < 4; ++mi)
        #pragma unroll
        for (int ni = 0; ni < 2; ++ni) acc[mi][ni] = (f32x4){0.f, 0.f, 0.f, 0.f};

    for (int k0 = 0; k0 < K; k0 += GBK) {
        #pragma unroll
        for (int i = 0; i < 2; ++i) {
            int c = i * 4 + wave;
            int row = c * 16 + lrow;
            const unsigned short* gp = A + (size_t)(bm + row) * K + k0 + lkoff;
            __builtin_amdgcn_global_load_lds(
                (const __attribute__((address_space(1))) void*)gp,
                (__attribute__((address_space(3))) void*)&As[c * 512], 16, 0, 0);
        }
        {
            int row = wave * 16 + lrow;
            const unsigned short* gp = Bt + (size_t)(bn + row) * K + k0 + lkoff;
            __builtin_amdgcn_global_load_lds(
                (const __attribute__((address_space(1))) void*)gp,
                (__attribute__((address_space(3))) void*)&Bs[wave * 512], 16, 0, 0);
        }
        __syncthreads();
        bf16x8 af[4], bfr[2];
        #pragma unroll
        for (int mi = 0; mi < 4; ++mi)
            af[mi] = *(const bf16x8*)&As[(wr * 64 + mi * 16 + row16) * GBK + q8];
        #pragma unroll
        for (int ni = 0; ni < 2; ++ni)
            bfr[ni] = *(const bf16x8*)&Bs[(wc * 32 + ni * 16 + row16) * GBK + q8];
        #pragma unroll
        for (int mi = 0; mi < 4; ++mi)
            #pragma unroll
            for (int ni = 0; ni < 2; ++ni)
                acc[mi][ni] = __builtin_amdgcn_mfma_f32_16x16x32_bf16(
                    af[mi], bfr[ni], acc[mi][ni], 0, 0, 0);
        __syncthreads();
    }

    int rbase = bm + wr * 64 + (lane >> 4) * 4;
    int cbase = bn + wc * 32 + (lane & 15);
    #pragma unroll
    for (int mi = 0; mi < 4; ++mi)
        #pragma unroll
        for (int ni = 0; ni < 2; ++ni)
            #pragma unroll
            for (int r = 0; r < 4; ++r)
                C[(size_t)(rbase + mi * 16 + r) * N + cbase + ni * 16] =
                    f2bf(acc[mi][ni][r]);
}

// ---------------------------------------------------------------------------
// Tiny layer-4 GEMM: C[M][16] (bf16) = A[M][128] (bf16) @ W[128][16] (fp32).
// ---------------------------------------------------------------------------
__global__ __launch_bounds__(256) void gemm4(const unsigned short* __restrict__ A,
                                             const float* __restrict__ W,
                                             unsigned short* __restrict__ C, int M) {
    __shared__ float Ws[128 * 16];
    int tid = threadIdx.x;
    for (int i = tid; i < 2048; i += 256) Ws[i] = W[i];
    __syncthreads();
    int node = blockIdx.x * 16 + (tid >> 4);
    int n = tid & 15;
    if (node >= M) return;
    const unsigned short* ap = A + (size_t)node * 128;
    float acc = 0.f;
    #pragma unroll 8
    for (int k = 0; k < 128; ++k)
        acc += bf2f(ap[k]) * Ws[k * 16 + n];
    C[(size_t)node * 16 + n] = f2bf(acc);
}

// ---------------------------------------------------------------------------
// e_src[n,H], e_dst[n,H]: per-(node,head) dot of bf16 h[n,h,:] with a_src/a_dst.
// ---------------------------------------------------------------------------
__global__ __launch_bounds__(64) void attn_halves(const unsigned short* __restrict__ h,
                                                  const float* __restrict__ a_src,
                                                  const float* __restrict__ a_dst,
                                                  float* __restrict__ e_src,
                                                  float* __restrict__ e_dst,
                                                  int H, int C) {
    int wid = blockIdx.x;          // node*H + head
    int head = wid % H;
    int lane = threadIdx.x;
    const unsigned short* hp = h + (size_t)wid * C;
    float s1 = 0.f, s2 = 0.f;
    for (int c0 = lane * 4; c0 < C; c0 += 256) {
        u16x4 hv = *(const u16x4*)&hp[c0];
        f32x4 as = *(const f32x4*)&a_src[head * C + c0];
        f32x4 ad = *(const f32x4*)&a_dst[head * C + c0];
        #pragma unroll
        for (int j = 0; j < 4; ++j) {
            float v = bf2f(hv[j]);
            s1 += v * as[j];
            s2 += v * ad[j];
        }
    }
    #pragma unroll
    for (int off = 32; off; off >>= 1) {
        s1 += __shfl_down(s1, off);
        s2 += __shfl_down(s2, off);
    }
    if (lane == 0) { e_src[wid] = s1; e_dst[wid] = s2; }
}

// ---------------------------------------------------------------------------
// Layer-1 aggregation (H=10, C=256): one wave per (node, head-pair).
// Lane covers 8 contiguous channels of one head; one dwordx4 gather per edge
// spans both head rows (1024 B). Per-head max/denom computed redundantly per
// lane (wave-uniform inputs) -> no cross-lane ops. Fused softmax + bias +
// LeakyReLU(0.1); bf16 packed output.
// ---------------------------------------------------------------------------
__global__ __launch_bounds__(64) void agg_l1(const unsigned short* __restrict__ h,
                                             const float* __restrict__ e_src,
                                             const float* __restrict__ e_dst,
                                             const int* __restrict__ row_ptr,
                                             const int* __restrict__ col,
                                             const float* __restrict__ bias,
                                             unsigned short* __restrict__ out) {
    const int H = 10;
    int wid  = blockIdx.x;            // node*5 + hp
    int node = wid / 5;
    int hp   = wid - node * 5;
    int lane = threadIdx.x;
    int sub  = lane >> 5;             // 0/1 within head pair
    int head = hp * 2 + sub;
    int cpos = lane & 31;             // 8 channels each
    int rs = row_ptr[node], re = row_ptr[node + 1];
    float edv = e_dst[node * H + head];

    // pass A: per-head segment max (redundant per lane)
    float mx = -INFINITY;
    for (int i = rs; i < re; ++i) {
        float v = lrelu02(e_src[col[i] * H + head] + edv);
        mx = fmaxf(mx, v);
    }

    // pass B: fused denom + weighted dwordx4 gather
    float dn = 0.f;
    float acc[8];
    #pragma unroll
    for (int k = 0; k < 8; ++k) acc[k] = 0.f;
    #pragma unroll 2
    for (int i = rs; i < re; ++i) {
        int s = col[i];
        float w = __expf(lrelu02(e_src[s * H + head] + edv) - mx);
        dn += w;
        u32x4 hv = *(const u32x4*)(h + (size_t)s * 2560 + head * 256 + cpos * 8);
        #pragma unroll
        for (int d = 0; d < 4; ++d) {
            acc[2 * d]     += w * bf2f((unsigned short)(hv[d] & 0xffffu));
            acc[2 * d + 1] += w * bf2f((unsigned short)(hv[d] >> 16));
        }
    }
    float rdn = 1.f / (dn + 1e-16f);

    const float* bp = bias + head * 256 + cpos * 8;
    u32x4 o;
    #pragma unroll
    for (int d = 0; d < 4; ++d) {
        float v0 = lrelu01(acc[2 * d] * rdn + bp[2 * d]);
        float v1 = lrelu01(acc[2 * d + 1] * rdn + bp[2 * d + 1]);
        o[d] = (unsigned int)f2bf(v0) | ((unsigned int)f2bf(v1) << 16);
    }
    *(u32x4*)(out + (size_t)node * 2560 + head * 256 + cpos * 8) = o;
}

// ---------------------------------------------------------------------------
// Layer-2 aggregation (H=8, C=56): one wave per node. Lane -> (head, 8-ch
// slot): 56 active lanes, one dwordx4 per edge covers the node's full 448-ch
// row (896 B). Redundant per-lane max/denom; no cross-lane ops.
// ---------------------------------------------------------------------------
__global__ __launch_bounds__(64) void agg_l2(const unsigned short* __restrict__ h,
                                             const float* __restrict__ e_src,
                                             const float* __restrict__ e_dst,
                                             const int* __restrict__ row_ptr,
                                             const int* __restrict__ col,
                                             const float* __restrict__ bias,
                                             unsigned short* __restrict__ out) {
    const int H = 8;
    int node = blockIdx.x;
    int lane = threadIdx.x;
    bool act = lane < 56;
    int head = act ? (lane / 7) : 0;
    int cpos = act ? (lane - head * 7) : 0;
    int rs = row_ptr[node], re = row_ptr[node + 1];
    float edv = e_dst[node * H + head];

    float mx = -INFINITY;
    for (int i = rs; i < re; ++i) {
        float v = lrelu02(e_src[col[i] * H + head] + edv);
        mx = fmaxf(mx, v);
    }

    float dn = 0.f;
    float acc[8];
    #pragma unroll
    for (int k = 0; k < 8; ++k) acc[k] = 0.f;
    #pragma unroll 2
    for (int i = rs; i < re; ++i) {
        int s = col[i];
        float w = __expf(lrelu02(e_src[s * H + head] + edv) - mx);
        dn += w;
        u32x4 hv = *(const u32x4*)(h + (size_t)s * 448 + head * 56 + cpos * 8);
        #pragma unroll
        for (int d = 0; d < 4; ++d) {
            acc[2 * d]     += w * bf2f((unsigned short)(hv[d] & 0xffffu));
            acc[2 * d + 1] += w * bf2f((unsigned short)(hv[d] >> 16));
        }
    }
    float rdn = 1.f / (dn + 1e-16f);

    if (act) {
        const float* bp = bias + head * 56 + cpos * 8;
        u32x4 o;
        #pragma unroll
        for (int d = 0; d < 4; ++d) {
            float v0 = lrelu01(acc[2 * d] * rdn + bp[2 * d]);
            float v1 = lrelu01(acc[2 * d + 1] * rdn + bp[2 * d + 1]);
            o[d] = (unsigned int)f2bf(v0) | ((unsigned int)f2bf(v1) << 16);
        }
        *(u32x4*)(out + (size_t)node * 448 + head * 56 + cpos * 8) = o;
    }
}

// ---------------------------------------------------------------------------
// Layer-3 aggregation (H=4, C=32): one wave per node, 16 active lanes
// (head = lane>>2, 8 ch per lane).
// ---------------------------------------------------------------------------
__global__ __launch_bounds__(64) void agg_l3(const unsigned short* __restrict__ h,
                                             const float* __restrict__ e_src,
                                             const float* __restrict__ e_dst,
                                             const int* __restrict__ row_ptr,
                                             const int* __restrict__ col,
                                             const float* __restrict__ bias,
                                             unsigned short* __restrict__ out) {
    const int H = 4;
    int node = blockIdx.x;
    int lane = threadIdx.x;
    bool act = lane < 16;
    int head = (lane >> 2) & 3;
    int cpos = lane & 3;
    int rs = row_ptr[node], re = row_ptr[node + 1];
    float edv = e_dst[node * H + head];

    float mx = -INFINITY;
    for (int i = rs; i < re; ++i) {
        float v = lrelu02(e_src[col[i] * H + head] + edv);
        mx = fmaxf(mx, v);
    }

    float dn = 0.f;
    float acc[8];
    #pragma unroll
    for (int k = 0; k < 8; ++k) acc[k] = 0.f;
    #pragma unroll 2
    for (int i = rs; i < re; ++i) {
        int s = col[i];
        float w = __expf(lrelu02(e_src[s * H + head] + edv) - mx);
        dn += w;
        u32x4 hv = *(const u32x4*)(h + (size_t)s * 128 + head * 32 + cpos * 8);
        #pragma unroll
        for (int d = 0; d < 4; ++d) {
            acc[2 * d]     += w * bf2f((unsigned short)(hv[d] & 0xffffu));
            acc[2 * d + 1] += w * bf2f((unsigned short)(hv[d] >> 16));
        }
    }
    float rdn = 1.f / (dn + 1e-16f);

    if (act) {
        const float* bp = bias + head * 32 + cpos * 8;
        u32x4 o;
        #pragma unroll
        for (int d = 0; d < 4; ++d) {
            float v0 = lrelu01(acc[2 * d] * rdn + bp[2 * d]);
            float v1 = lrelu01(acc[2 * d + 1] * rdn + bp[2 * d + 1]);
            o[d] = (unsigned int)f2bf(v0) | ((unsigned int)f2bf(v1) << 16);
        }
        *(u32x4*)(out + (size_t)node * 128 + head * 32 + cpos * 8) = o;
    }
}

// ---------------------------------------------------------------------------
// Layer-4 fused: aggregate (H=1, C=16) + bias + LeakyReLU(0.1) + row softmax.
// One wave per node; lane&7 covers 2 channels (dword). All lanes redundant.
// ---------------------------------------------------------------------------
__global__ __launch_bounds__(64) void agg4_softmax(const unsigned int* __restrict__ h2,
                                                   const float* __restrict__ e_src,
                                                   const float* __restrict__ e_dst,
                                                   const int* __restrict__ row_ptr,
                                                   const int* __restrict__ col,
                                                   const float* __restrict__ bias,
                                                   float* __restrict__ out) {
    int node = blockIdx.x;
    int lane = threadIdx.x;
    int cpos = lane & 7;
    int rs = row_ptr[node], re = row_ptr[node + 1];
    float edv = e_dst[node];

    float mx = -INFINITY;
    for (int i = rs; i < re; ++i) {
        float v = lrelu02(e_src[col[i]] + edv);
        mx = fmaxf(mx, v);
    }

    float dn = 0.f, a0 = 0.f, a1 = 0.f;
    for (int i = rs; i < re; ++i) {
        int s = col[i];
        float w = __expf(lrelu02(e_src[s] + edv) - mx);
        dn += w;
        unsigned int hv = h2[(size_t)s * 8 + cpos];
        a0 += w * bf2f((unsigned short)(hv & 0xffffu));
        a1 += w * bf2f((unsigned short)(hv >> 16));
    }
    float rdn = 1.f / (dn + 1e-16f);
    float v0 = lrelu01(a0 * rdn + bias[2 * cpos]);
    float v1 = lrelu01(a1 * rdn + bias[2 * cpos + 1]);

    // softmax over 16 values per aligned 8-lane group
    float m = fmaxf(v0, v1);
    #pragma unroll
    for (int off = 4; off; off >>= 1) m = fmaxf(m, __shfl_xor(m, off));
    float e0 = __expf(v0 - m), e1 = __expf(v1 - m);
    float s = e0 + e1;
    #pragma unroll
    for (int off = 4; off; off >>= 1) s += __shfl_xor(s, off);
    float r = 1.f / s;
    if (lane < 8) {
        out[node * 16 + 2 * cpos]     = e0 * r;
        out[node * 16 + 2 * cpos + 1] = e1 * r;
    }
}

// ---------------------------------------------------------------------------
extern "C" void kernel_launch(void* const* d_in, const int* in_sizes, int n_in,
                              void* d_out, int out_size, void* d_ws, size_t ws_size,
                              hipStream_t stream) {
    const float* x   = (const float*)d_in[0];
    const int*   ei  = (const int*)d_in[1];
    const float* W1  = (const float*)d_in[2];
    const float* as1 = (const float*)d_in[3];
    const float* ad1 = (const float*)d_in[4];
    const float* b1  = (const float*)d_in[5];
    const float* W2  = (const float*)d_in[6];
    const float* as2 = (const float*)d_in[7];
    const float* ad2 = (const float*)d_in[8];
    const float* b2  = (const float*)d_in[9];
    const float* W3  = (const float*)d_in[10];
    const float* as3 = (const float*)d_in[11];
    const float* ad3 = (const float*)d_in[12];
    const float* b3  = (const float*)d_in[13];
    const float* W4  = (const float*)d_in[14];
    const float* as4 = (const float*)d_in[15];
    const float* ad4 = (const float*)d_in[16];
    const float* b4  = (const float*)d_in[17];

    char* ws = (char*)d_ws;
    size_t off = 0;
    auto alloc = [&](size_t bytes) -> void* {
        void* p = ws + off;
        off = (off + bytes + 255) & ~(size_t)255;
        return p;
    };
    unsigned short* hbuf = (unsigned short*)alloc((size_t)MPAD * 2560 * sizeof(short)); // GEMM out / attn input
    unsigned short* abuf = (unsigned short*)alloc((size_t)MPAD * 2560 * sizeof(short)); // bf16 GEMM A input
    unsigned short* W1t  = (unsigned short*)alloc((size_t)2560 * 128 * sizeof(short));
    unsigned short* W2t  = (unsigned short*)alloc((size_t)448 * 2560 * sizeof(short));
    unsigned short* W3t  = (unsigned short*)alloc((size_t)128 * 448 * sizeof(short));
    float* e_src  = (float*)alloc((size_t)NNODES * 10 * sizeof(float));
    float* e_dst  = (float*)alloc((size_t)NNODES * 10 * sizeof(float));
    int* indeg    = (int*)alloc(NNODES * sizeof(int));
    int* row_ptr  = (int*)alloc((NNODES + 1) * sizeof(int));
    int* cursor   = (int*)alloc(NNODES * sizeof(int));
    int* col      = (int*)alloc(ETOT * sizeof(int));
    (void)ws_size;

    // ---- CSR build ----
    hipMemsetAsync(indeg, 0, NNODES * sizeof(int), stream);
    int eb = (ETOT + 255) / 256;
    count_deg<<<eb, 256, 0, stream>>>(ei, indeg, NEDGES, NNODES);
    scan_rowptr<<<1, 1024, 0, stream>>>(indeg, row_ptr, cursor, NNODES);
    scatter_edges<<<eb, 256, 0, stream>>>(ei, cursor, col, NEDGES, NNODES);

    // ---- weight transposes + x convert ----
    transpose_bf16<<<dim3(2560 / 32, 128 / 32), dim3(32, 8), 0, stream>>>(W1, W1t, 128, 2560);
    transpose_bf16<<<dim3(448 / 32, 2560 / 32), dim3(32, 8), 0, stream>>>(W2, W2t, 2560, 448);
    transpose_bf16<<<dim3(128 / 32, 448 / 32), dim3(32, 8), 0, stream>>>(W3, W3t, 448, 128);
    convert_bf16<<<(NNODES * 128 + 255) / 256, 256, 0, stream>>>(x, abuf, NNODES * 128);

    const int Mb = MPAD / GBM;   // 79

    // ---- Layer 1: 128 -> 10 heads x 256, concat ----
    gemm_mfma<<<dim3(2560 / GBN, Mb), 256, 0, stream>>>(abuf, W1t, hbuf, 2560, 128);
    attn_halves<<<NNODES * 10, 64, 0, stream>>>(hbuf, as1, ad1, e_src, e_dst, 10, 256);
    agg_l1<<<NNODES * 5, 64, 0, stream>>>(hbuf, e_src, e_dst, row_ptr, col, b1, abuf);

    // ---- Layer 2: 2560 -> 8 heads x 56, concat ----
    gemm_mfma<<<dim3(448 / GBN, Mb), 256, 0, stream>>>(abuf, W2t, hbuf, 448, 2560);
    attn_halves<<<NNODES * 8, 64, 0, stream>>>(hbuf, as2, ad2, e_src, e_dst, 8, 56);
    agg_l2<<<NNODES, 64, 0, stream>>>(hbuf, e_src, e_dst, row_ptr, col, b2, abuf);

    // ---- Layer 3: 448 -> 4 heads x 32, concat ----
    gemm_mfma<<<dim3(128 / GBN, Mb), 256, 0, stream>>>(abuf, W3t, hbuf, 128, 448);
    attn_halves<<<NNODES * 4, 64, 0, stream>>>(hbuf, as3, ad3, e_src, e_dst, 4, 32);
    agg_l3<<<NNODES, 64, 0, stream>>>(hbuf, e_src, e_dst, row_ptr, col, b3, abuf);

    // ---- Layer 4: 128 -> 1 head x 16, mean(=identity), + softmax fused ----
    gemm4<<<(NNODES + 15) / 16, 256, 0, stream>>>(abuf, W4, hbuf, NNODES);
    attn_halves<<<NNODES, 64, 0, stream>>>(hbuf, as4, ad4, e_src, e_dst, 1, 16);
    agg4_softmax<<<NNODES, 64, 0, stream>>>(
        (const unsigned int*)hbuf, e_src, e_dst, row_ptr, col, b4, (float*)d_out);
}